// Round 1
// baseline (281.784 us; speedup 1.0000x reference)
//
#include <hip/hip_runtime.h>

// Problem constants (from setup_inputs): x is (B=2, C=128, H=96, W=96) fp32.
#define BN   2
#define CN   128
#define HN   96
#define WN   96
#define HW   (HN * WN)          // 9216
#define NPIX (BN * HW)          // 18432
#define NTOT (BN * CN * HW)     // 2359296
#define EPSV 1e-8f

// Kernel 1: per-pixel squared L2 norm over channels.
// Thread per pixel; channel loop strides HW -> loads coalesce across threads.
__global__ void k_normsq(const float* __restrict__ x, float* __restrict__ n2) {
    int p = blockIdx.x * blockDim.x + threadIdx.x;
    if (p >= NPIX) return;
    int b = p / HW, hw = p % HW;
    const float* xb = x + (size_t)b * CN * HW + hw;
    float acc = 0.f;
#pragma unroll 8
    for (int c = 0; c < CN; ++c) {
        float v = xb[(size_t)c * HW];
        acc += v * v;
    }
    n2[p] = acc;
}

// Kernel 2: per-pixel 5x5 cosine-sim count -> mask m = sqrt(count).
// Thread per pixel. 24 dot accumulators; OOB neighbors read center (discarded)
// to keep loads uniform, and are forced to sim=0 (always < t2=0.3 -> count).
__global__ void k_count(const float* __restrict__ x, const float* __restrict__ n2,
                        const float* __restrict__ thr2p, float* __restrict__ mask) {
    int p = blockIdx.x * blockDim.x + threadIdx.x;
    if (p >= NPIX) return;
    const float t2 = *thr2p;
    int b = p / HW, hw = p % HW;
    int h = hw / WN, w = hw % WN;
    const float* xb = x + (size_t)b * CN * HW;

    int off[24];
    unsigned valid = 0;
    {
        int j = 0;
        for (int dy = -2; dy <= 2; ++dy)
            for (int dx = -2; dx <= 2; ++dx) {
                if (dy == 0 && dx == 0) continue;
                int hh = h + dy, ww = w + dx;
                bool ok = (hh >= 0) && (hh < HN) && (ww >= 0) && (ww < WN);
                off[j] = ok ? (hh * WN + ww) : hw;
                if (ok) valid |= (1u << j);
                ++j;
            }
    }

    float dot[24];
#pragma unroll
    for (int j = 0; j < 24; ++j) dot[j] = 0.f;

#pragma unroll 2
    for (int c = 0; c < CN; ++c) {
        const float* row = xb + (size_t)c * HW;
        float ctr = row[hw];
#pragma unroll
        for (int j = 0; j < 24; ++j) dot[j] += ctr * row[off[j]];
    }

    float nc = sqrtf(n2[p]);
    int count = 0;
#pragma unroll
    for (int j = 0; j < 24; ++j) {
        float sim = 0.f;
        if (valid & (1u << j)) {
            float npn = sqrtf(n2[b * HW + off[j]]);
            sim = dot[j] / fmaxf(nc * npn, EPSV);
        }
        count += (sim < t2) ? 1 : 0;
    }
    mask[p] = sqrtf((float)count);
}

// Kernel 3: out = x * m + x (m broadcast over channels), float4 vectorized.
__global__ void k_apply(const float* __restrict__ x, const float* __restrict__ mask,
                        float* __restrict__ out) {
    int t = blockIdx.x * blockDim.x + threadIdx.x;
    int i = t * 4;
    if (i >= NTOT) return;
    int b = i / (CN * HW);
    int hw = i % HW;                 // (c*HW) is a multiple of HW
    const float4 xv = *(const float4*)(x + i);
    const float4 mv = *(const float4*)(mask + b * HW + hw);  // hw % 4 == 0
    float4 o;
    o.x = xv.x * mv.x + xv.x;
    o.y = xv.y * mv.y + xv.y;
    o.z = xv.z * mv.z + xv.z;
    o.w = xv.w * mv.w + xv.w;
    *(float4*)(out + i) = o;
}

extern "C" void kernel_launch(void* const* d_in, const int* in_sizes, int n_in,
                              void* d_out, int out_size, void* d_ws, size_t ws_size,
                              hipStream_t stream) {
    const float* x    = (const float*)d_in[0];
    // d_in[1] = edge_threshold1 (unused: cosine sim is invariant to the
    //           per-pixel positive rescale x_mask = x*(1+m1))
    const float* thr2 = (const float*)d_in[2];
    float* out = (float*)d_out;

    float* n2   = (float*)d_ws;                 // NPIX floats
    float* mask = (float*)d_ws + NPIX;          // NPIX floats (sqrt(count))

    // K1: norm^2 map. 288 blocks x 64 threads.
    k_normsq<<<NPIX / 64, 64, 0, stream>>>(x, n2);
    // K2: count/mask map.
    k_count<<<NPIX / 64, 64, 0, stream>>>(x, n2, thr2, mask);
    // K3: elementwise apply. NTOT/4 lanes.
    k_apply<<<(NTOT / 4 + 255) / 256, 256, 0, stream>>>(x, mask, out);
}

// Round 2
// 103.907 us; speedup vs baseline: 2.7119x; 2.7119x over previous
//
#include <hip/hip_runtime.h>

// x is (B=2, C=128, H=96, W=96) fp32.
#define BN   2
#define CN   128
#define HN   96
#define WN   96
#define HW   (HN * WN)          // 9216
#define NPIX (BN * HW)          // 18432
#define NP4  (NPIX / 4)         // 4608
#define NTOT (BN * CN * HW)     // 2359296
#define NMAP 13                 // map 0 = norm^2, maps 1..12 = positive-offset dots
#define EPSV 1e-8f

// Positive half-plane offsets (dy,dx), maps 1..12. dot(p, p+d) == dot(p+d, p),
// so 12 maps cover all 24 neighbor directions.
constexpr int ODY[12] = {0, 0, 1, 1, 1, 1, 1, 2, 2, 2, 2, 2};
constexpr int ODX[12] = {1, 2, -2, -1, 0, 1, 2, -2, -1, 0, 1, 2};

// Kernel A: partial dot/norm maps over a channel chunk.
// Thread = (chunk, 4 horizontally-adjacent pixels). Per channel: 3 rows x 3
// aligned float4 loads -> 12-float register windows; 52 FMAs all in registers.
// OOB rows/cols contribute 0 (reference zero-pads); loads never leave the row.
template<int CPC>   // channels per chunk
__global__ void k_partial(const float* __restrict__ x, float* __restrict__ P) {
    int p4 = blockIdx.x * blockDim.x + threadIdx.x;   // 0..NP4-1
    int chunk = blockIdx.y;
    int nch = gridDim.y;
    int pix = p4 * 4;
    int b = pix / HW;
    int hw = pix - b * HW;
    int h = hw / WN;
    int w = hw - h * WN;                              // multiple of 4
    const float* xb = x + ((size_t)b * CN + (size_t)chunk * CPC) * HW + h * WN + w;

    float acc[NMAP][4];
#pragma unroll
    for (int m = 0; m < NMAP; ++m)
#pragma unroll
        for (int i = 0; i < 4; ++i) acc[m][i] = 0.f;

    for (int cc = 0; cc < CPC; ++cc) {
        const float* cp = xb + (size_t)cc * HW;
        float r[3][12];
#pragma unroll
        for (int ry = 0; ry < 3; ++ry) {
            float4 a0 = make_float4(0.f, 0.f, 0.f, 0.f);
            float4 a1 = make_float4(0.f, 0.f, 0.f, 0.f);
            float4 a2 = make_float4(0.f, 0.f, 0.f, 0.f);
            if (h + ry < HN) {                         // ry==0 always true
                const float* rp = cp + ry * WN;
                if (w > 0)       a0 = *(const float4*)(rp - 4);   // cols w-4..w-1
                a1 = *(const float4*)(rp);                         // cols w..w+3
                if (w + 4 < WN)  a2 = *(const float4*)(rp + 4);   // cols w+4..w+7
            }
            r[ry][0] = a0.x; r[ry][1] = a0.y; r[ry][2]  = a0.z; r[ry][3]  = a0.w;
            r[ry][4] = a1.x; r[ry][5] = a1.y; r[ry][6]  = a1.z; r[ry][7]  = a1.w;
            r[ry][8] = a2.x; r[ry][9] = a2.y; r[ry][10] = a2.z; r[ry][11] = a2.w;
        }
#pragma unroll
        for (int i = 0; i < 4; ++i) {
            float c = r[0][4 + i];
            acc[0][i] += c * c;
#pragma unroll
            for (int j = 0; j < 12; ++j)
                acc[j + 1][i] += c * r[ODY[j]][4 + i + ODX[j]];
        }
    }

#pragma unroll
    for (int m = 0; m < NMAP; ++m) {
        float4 v = make_float4(acc[m][0], acc[m][1], acc[m][2], acc[m][3]);
        *(float4*)(P + ((size_t)m * nch + chunk) * NPIX + pix) = v;
    }
}

// Kernel B1: reduce chunk partials -> full maps D[NMAP][NPIX].
__global__ void k_reduce(const float* __restrict__ P, float* __restrict__ D, int nch) {
    int t = blockIdx.x * blockDim.x + threadIdx.x;    // NMAP*NP4 threads
    if (t >= NMAP * NP4) return;
    int m = t / NP4, p4 = t - m * NP4;
    int pix = p4 * 4;
    float4 s = make_float4(0.f, 0.f, 0.f, 0.f);
    for (int ch = 0; ch < nch; ++ch) {
        float4 v = *(const float4*)(P + ((size_t)m * nch + ch) * NPIX + pix);
        s.x += v.x; s.y += v.y; s.z += v.z; s.w += v.w;
    }
    *(float4*)(D + (size_t)m * NPIX + pix) = s;
}

// Kernel B2: per-pixel 24-direction sim count -> mask = sqrt(count).
// Positive dir d: dot = D[map][p].  Negative dir -d: dot = D[map][p-d].
// OOB neighbor -> sim = 0 (< t2) -> always counted.
__global__ void k_count2(const float* __restrict__ D, const float* __restrict__ thr2p,
                         float* __restrict__ mask) {
    int p = blockIdx.x * blockDim.x + threadIdx.x;
    if (p >= NPIX) return;
    const float t2 = *thr2p;
    int b = p / HW;
    int hw = p - b * HW;
    int h = hw / WN, w = hw - h * WN;
    float nc = sqrtf(D[p]);                            // map 0 = norm^2
    int count = 0;
#pragma unroll
    for (int j = 0; j < 12; ++j) {
        const int dy = ODY[j], dx = ODX[j];
        const float* Dj = D + (size_t)(j + 1) * NPIX;
        // positive direction: neighbor (h+dy, w+dx)
        {
            float sim = 0.f;
            if (h + dy < HN && w + dx >= 0 && w + dx < WN) {
                int q = p + dy * WN + dx;
                float nn = sqrtf(D[q]);
                sim = Dj[p] / fmaxf(nc * nn, EPSV);
            }
            count += (sim < t2) ? 1 : 0;
        }
        // negative direction: neighbor (h-dy, w-dx); dot stored at that neighbor
        {
            float sim = 0.f;
            if (h - dy >= 0 && w - dx >= 0 && w - dx < WN) {
                int q = p - (dy * WN + dx);
                float nn = sqrtf(D[q]);
                sim = Dj[q] / fmaxf(nc * nn, EPSV);
            }
            count += (sim < t2) ? 1 : 0;
        }
    }
    mask[p] = sqrtf((float)count);
}

// Kernel C: out = x * m + x, float4.
__global__ void k_apply(const float* __restrict__ x, const float* __restrict__ mask,
                        float* __restrict__ out) {
    int t = blockIdx.x * blockDim.x + threadIdx.x;
    int i = t * 4;
    if (i >= NTOT) return;
    int b = i / (CN * HW);
    int hw = i % HW;                                   // multiple of 4
    const float4 xv = *(const float4*)(x + i);
    const float4 mv = *(const float4*)(mask + b * HW + hw);
    float4 o;
    o.x = xv.x * mv.x + xv.x;
    o.y = xv.y * mv.y + xv.y;
    o.z = xv.z * mv.z + xv.z;
    o.w = xv.w * mv.w + xv.w;
    *(float4*)(out + i) = o;
}

extern "C" void kernel_launch(void* const* d_in, const int* in_sizes, int n_in,
                              void* d_out, int out_size, void* d_ws, size_t ws_size,
                              hipStream_t stream) {
    const float* x    = (const float*)d_in[0];
    // d_in[1] = edge_threshold1: unused — cosine sim is invariant under the
    // per-pixel positive rescale x_mask = x*(1+m1), so the 9x9 pass is dead.
    const float* thr2 = (const float*)d_in[2];
    float* out = (float*)d_out;

    float* D    = (float*)d_ws;                        // NMAP*NPIX floats
    float* mask = D + (size_t)NMAP * NPIX;             // NPIX floats
    float* P    = mask + NPIX;                         // NMAP*nch*NPIX floats

    // Pick channel-chunk count by available workspace (constant across calls).
    size_t base_bytes = (size_t)(NMAP + 1) * NPIX * 4;
    int nch = 16;
    while (nch > 1 && base_bytes + (size_t)NMAP * nch * NPIX * 4 > ws_size) nch >>= 1;

    dim3 gA(NP4 / 256, nch);
    switch (nch) {
        case 16: k_partial<8>  <<<gA, 256, 0, stream>>>(x, P); break;
        case 8:  k_partial<16> <<<gA, 256, 0, stream>>>(x, P); break;
        case 4:  k_partial<32> <<<gA, 256, 0, stream>>>(x, P); break;
        case 2:  k_partial<64> <<<gA, 256, 0, stream>>>(x, P); break;
        default: k_partial<128><<<gA, 256, 0, stream>>>(x, P); break;
    }
    k_reduce<<<(NMAP * NP4) / 256, 256, 0, stream>>>(P, D, nch);
    k_count2<<<NPIX / 256, 256, 0, stream>>>(D, thr2, mask);
    k_apply<<<(NTOT / 4) / 256, 256, 0, stream>>>(x, mask, out);
}

// Round 3
// 91.085 us; speedup vs baseline: 3.0936x; 1.1408x over previous
//
#include <hip/hip_runtime.h>

// x is (B=2, C=128, H=96, W=96) fp32.
#define BN   2
#define CN   128
#define HN   96
#define WN   96
#define HW   (HN * WN)          // 9216
#define NPIX (BN * HW)          // 18432
#define NP4  (NPIX / 4)         // 4608
#define NTOT (BN * CN * HW)     // 2359296
#define NMAP 13                 // map 0 = norm^2, maps 1..12 = positive-offset dots
#define EPSV 1e-8f

// Positive half-plane offsets (dy,dx), maps 1..12. dot(p, p+d) == dot(p+d, p).
constexpr int ODY[12] = {0, 0, 1, 1, 1, 1, 1, 2, 2, 2, 2, 2};
constexpr int ODX[12] = {1, 2, -2, -1, 0, 1, 2, -2, -1, 0, 1, 2};

// Kernel A: partial dot/norm maps over a channel chunk.
// Thread = (chunk, 4 horizontally-adjacent pixels). Per channel: 3 rows x 3
// aligned float4 loads -> 12-float register window; 52 FMAs in registers.
// 64-thread blocks so the grid spreads across all 256 CUs.
template<int CPC>   // channels per chunk
__global__ void __launch_bounds__(64) k_partial(const float* __restrict__ x,
                                                float* __restrict__ P) {
    int p4 = blockIdx.x * blockDim.x + threadIdx.x;   // 0..NP4-1
    int chunk = blockIdx.y;
    int nch = gridDim.y;
    int pix = p4 * 4;
    int b = pix / HW;
    int hw = pix - b * HW;
    int h = hw / WN;
    int w = hw - h * WN;                              // multiple of 4
    const float* xb = x + ((size_t)b * CN + (size_t)chunk * CPC) * HW + h * WN + w;

    float acc[NMAP][4];
#pragma unroll
    for (int m = 0; m < NMAP; ++m)
#pragma unroll
        for (int i = 0; i < 4; ++i) acc[m][i] = 0.f;

    for (int cc = 0; cc < CPC; ++cc) {
        const float* cp = xb + (size_t)cc * HW;
        float r[3][12];
#pragma unroll
        for (int ry = 0; ry < 3; ++ry) {
            float4 a0 = make_float4(0.f, 0.f, 0.f, 0.f);
            float4 a1 = make_float4(0.f, 0.f, 0.f, 0.f);
            float4 a2 = make_float4(0.f, 0.f, 0.f, 0.f);
            if (h + ry < HN) {                         // ry==0 always true
                const float* rp = cp + ry * WN;
                if (w > 0)       a0 = *(const float4*)(rp - 4);   // cols w-4..w-1
                a1 = *(const float4*)(rp);                         // cols w..w+3
                if (w + 4 < WN)  a2 = *(const float4*)(rp + 4);   // cols w+4..w+7
            }
            r[ry][0] = a0.x; r[ry][1] = a0.y; r[ry][2]  = a0.z; r[ry][3]  = a0.w;
            r[ry][4] = a1.x; r[ry][5] = a1.y; r[ry][6]  = a1.z; r[ry][7]  = a1.w;
            r[ry][8] = a2.x; r[ry][9] = a2.y; r[ry][10] = a2.z; r[ry][11] = a2.w;
        }
#pragma unroll
        for (int i = 0; i < 4; ++i) {
            float c = r[0][4 + i];
            acc[0][i] += c * c;
#pragma unroll
            for (int j = 0; j < 12; ++j)
                acc[j + 1][i] += c * r[ODY[j]][4 + i + ODX[j]];
        }
    }

#pragma unroll
    for (int m = 0; m < NMAP; ++m) {
        float4 v = make_float4(acc[m][0], acc[m][1], acc[m][2], acc[m][3]);
        *(float4*)(P + ((size_t)m * nch + chunk) * NPIX + pix) = v;
    }
}

// Kernel B: reduce chunk partials -> full maps D[NMAP][NPIX].
__global__ void __launch_bounds__(64) k_reduce(const float* __restrict__ P,
                                               float* __restrict__ D, int nch) {
    int t = blockIdx.x * blockDim.x + threadIdx.x;    // NMAP*NP4 threads
    if (t >= NMAP * NP4) return;
    int m = t / NP4, p4 = t - m * NP4;
    int pix = p4 * 4;
    float4 s = make_float4(0.f, 0.f, 0.f, 0.f);
    for (int ch = 0; ch < nch; ++ch) {
        float4 v = *(const float4*)(P + ((size_t)m * nch + ch) * NPIX + pix);
        s.x += v.x; s.y += v.y; s.z += v.z; s.w += v.w;
    }
    *(float4*)(D + (size_t)m * NPIX + pix) = s;
}

// Kernel C: fused count + apply. Thread = (pixel, channel-half).
// Computes mask = sqrt(#{sim < t2}) from the 13 maps, then streams its 64
// channels: out = x * (1 + mask). OOB neighbor -> sim = 0 -> always counted.
template<int CSPLIT>
__global__ void __launch_bounds__(64) k_maskapply(const float* __restrict__ x,
                                                  const float* __restrict__ D,
                                                  const float* __restrict__ thr2p,
                                                  float* __restrict__ out) {
    int p = blockIdx.x * blockDim.x + threadIdx.x;    // pixel
    if (p >= NPIX) return;
    int cg = blockIdx.y;
    const float t2 = *thr2p;
    int b = p / HW;
    int hw = p - b * HW;
    int h = hw / WN, w = hw - h * WN;

    float nc = sqrtf(D[p]);                           // map 0 = norm^2
    int count = 0;
#pragma unroll
    for (int j = 0; j < 12; ++j) {
        const int dy = ODY[j], dx = ODX[j];
        const float* Dj = D + (size_t)(j + 1) * NPIX;
        // positive direction: neighbor (h+dy, w+dx); dot stored at p
        {
            float sim = 0.f;
            if (h + dy < HN && w + dx >= 0 && w + dx < WN) {
                int q = p + dy * WN + dx;
                sim = Dj[p] / fmaxf(nc * sqrtf(D[q]), EPSV);
            }
            count += (sim < t2) ? 1 : 0;
        }
        // negative direction: neighbor q = p - d; dot stored at q
        {
            float sim = 0.f;
            if (h - dy >= 0 && w - dx >= 0 && w - dx < WN) {
                int q = p - (dy * WN + dx);
                sim = Dj[q] / fmaxf(nc * sqrtf(D[q]), EPSV);
            }
            count += (sim < t2) ? 1 : 0;
        }
    }
    float s = 1.f + sqrtf((float)count);

    constexpr int CG = CN / CSPLIT;
    const float* xp = x   + ((size_t)b * CN + (size_t)cg * CG) * HW + hw;
    float*       op = out + ((size_t)b * CN + (size_t)cg * CG) * HW + hw;
#pragma unroll 8
    for (int c = 0; c < CG; ++c)
        op[(size_t)c * HW] = xp[(size_t)c * HW] * s;
}

extern "C" void kernel_launch(void* const* d_in, const int* in_sizes, int n_in,
                              void* d_out, int out_size, void* d_ws, size_t ws_size,
                              hipStream_t stream) {
    const float* x    = (const float*)d_in[0];
    // d_in[1] = edge_threshold1: unused — cosine sim is invariant under the
    // per-pixel positive rescale x_mask = x*(1+m1), so the 9x9 pass is dead.
    const float* thr2 = (const float*)d_in[2];
    float* out = (float*)d_out;

    float* D = (float*)d_ws;                          // NMAP*NPIX floats
    float* P = D + (size_t)NMAP * NPIX;               // NMAP*nch*NPIX floats

    size_t base_bytes = (size_t)NMAP * NPIX * 4;
    int nch = 8;
    while (nch > 1 && base_bytes + (size_t)NMAP * nch * NPIX * 4 > ws_size) nch >>= 1;

    dim3 gA(NP4 / 64, nch);
    switch (nch) {
        case 8:  k_partial<16> <<<gA, 64, 0, stream>>>(x, P); break;
        case 4:  k_partial<32> <<<gA, 64, 0, stream>>>(x, P); break;
        case 2:  k_partial<64> <<<gA, 64, 0, stream>>>(x, P); break;
        default: k_partial<128><<<gA, 64, 0, stream>>>(x, P); break;
    }
    k_reduce<<<(NMAP * NP4 + 63) / 64, 64, 0, stream>>>(P, D, nch);
    k_maskapply<2><<<dim3(NPIX / 64, 2), 64, 0, stream>>>(x, D, thr2, out);
}

// Round 4
// 87.929 us; speedup vs baseline: 3.2047x; 1.0359x over previous
//
#include <hip/hip_runtime.h>

// x is (B=2, C=128, H=96, W=96) fp32.
#define BN   2
#define CN   128
#define HN   96
#define WN   96
#define HW   (HN * WN)          // 9216
#define NPIX (BN * HW)          // 18432
#define NP4  (NPIX / 4)         // 4608
#define NMAP 13                 // map 0 = norm^2, maps 1..12 = positive-offset dots
#define EPSV 1e-8f

// Positive half-plane offsets (dy,dx), maps 1..12. dot(p, p+d) == dot(p+d, p).
constexpr int ODY[12] = {0, 0, 1, 1, 1, 1, 1, 2, 2, 2, 2, 2};
constexpr int ODX[12] = {1, 2, -2, -1, 0, 1, 2, -2, -1, 0, 1, 2};

// Kernel 1: full dot/norm maps D[13][NPIX] in one pass.
// Block = (8 px4-lanes x 32 channel-slices), CPC=4 channels per slice.
// Grid = 576 blocks = 2304 waves = 9 waves/CU for latency hiding.
// Per channel: 3 rows x 3 aligned float4 loads -> 12-float register window,
// 52 FMAs in registers. Cross-slice sum via staged LDS reduction (no P buffer,
// no second kernel). OOB rows/cols contribute 0 (reference zero-pads).
__global__ void __launch_bounds__(256) k_maps(const float* __restrict__ x,
                                              float* __restrict__ D) {
    const int tx = threadIdx.x;                        // 0..7  (px4 lane)
    const int ty = threadIdx.y;                        // 0..31 (channel slice)
    int p4 = blockIdx.x * 8 + tx;                      // 0..NP4-1
    int pix = p4 * 4;
    int b = pix / HW;
    int hw = pix - b * HW;
    int h = hw / WN;
    int w = hw - h * WN;                               // multiple of 4
    const float* xb = x + ((size_t)b * CN + (size_t)ty * 4) * HW + h * WN + w;

    float acc[NMAP][4];
#pragma unroll
    for (int m = 0; m < NMAP; ++m)
#pragma unroll
        for (int i = 0; i < 4; ++i) acc[m][i] = 0.f;

#pragma unroll
    for (int cc = 0; cc < 4; ++cc) {
        const float* cp = xb + (size_t)cc * HW;
        float r[3][12];
#pragma unroll
        for (int ry = 0; ry < 3; ++ry) {
            float4 a0 = make_float4(0.f, 0.f, 0.f, 0.f);
            float4 a1 = make_float4(0.f, 0.f, 0.f, 0.f);
            float4 a2 = make_float4(0.f, 0.f, 0.f, 0.f);
            if (h + ry < HN) {                         // ry==0 always true
                const float* rp = cp + ry * WN;
                if (w > 0)       a0 = *(const float4*)(rp - 4);   // cols w-4..w-1
                a1 = *(const float4*)(rp);                         // cols w..w+3
                if (w + 4 < WN)  a2 = *(const float4*)(rp + 4);   // cols w+4..w+7
            }
            r[ry][0] = a0.x; r[ry][1] = a0.y; r[ry][2]  = a0.z; r[ry][3]  = a0.w;
            r[ry][4] = a1.x; r[ry][5] = a1.y; r[ry][6]  = a1.z; r[ry][7]  = a1.w;
            r[ry][8] = a2.x; r[ry][9] = a2.y; r[ry][10] = a2.z; r[ry][11] = a2.w;
        }
#pragma unroll
        for (int i = 0; i < 4; ++i) {
            float c = r[0][4 + i];
            acc[0][i] += c * c;
#pragma unroll
            for (int j = 0; j < 12; ++j)
                acc[j + 1][i] += c * r[ODY[j]][4 + i + ODX[j]];
        }
    }

    // Staged LDS reduction over the 32 slices: 16->8->4->2->1.
    // Inner dim padded 52->53: write banks = (tx*53 + mi) % 32, gcd(53,32)=1
    // -> <=2-way conflicts (free per m136).
    __shared__ float red[16][8][53];
#pragma unroll
    for (int s = 16; s >= 1; s >>= 1) {
        if (ty >= s && ty < 2 * s) {
#pragma unroll
            for (int m = 0; m < NMAP; ++m)
#pragma unroll
                for (int i = 0; i < 4; ++i)
                    red[ty - s][tx][m * 4 + i] = acc[m][i];
        }
        __syncthreads();
        if (ty < s) {
#pragma unroll
            for (int m = 0; m < NMAP; ++m)
#pragma unroll
                for (int i = 0; i < 4; ++i)
                    acc[m][i] += red[ty][tx][m * 4 + i];
        }
        __syncthreads();
    }

    if (ty == 0) {
#pragma unroll
        for (int m = 0; m < NMAP; ++m)
            *(float4*)(D + (size_t)m * NPIX + pix) =
                make_float4(acc[m][0], acc[m][1], acc[m][2], acc[m][3]);
    }
}

// Kernel 2: fused count + apply. Thread = (pixel, channel-quarter).
// mask = sqrt(#{sim < t2}) from the 13 maps, then stream 32 channels:
// out = x * (1 + mask). OOB neighbor -> sim = 0 -> always counted.
template<int CSPLIT>
__global__ void __launch_bounds__(64) k_maskapply(const float* __restrict__ x,
                                                  const float* __restrict__ D,
                                                  const float* __restrict__ thr2p,
                                                  float* __restrict__ out) {
    int p = blockIdx.x * blockDim.x + threadIdx.x;     // pixel
    if (p >= NPIX) return;
    int cg = blockIdx.y;
    const float t2 = *thr2p;
    int b = p / HW;
    int hw = p - b * HW;
    int h = hw / WN, w = hw - h * WN;

    float nc = sqrtf(D[p]);                            // map 0 = norm^2
    int count = 0;
#pragma unroll
    for (int j = 0; j < 12; ++j) {
        const int dy = ODY[j], dx = ODX[j];
        const float* Dj = D + (size_t)(j + 1) * NPIX;
        // positive direction: neighbor (h+dy, w+dx); dot stored at p
        {
            float sim = 0.f;
            if (h + dy < HN && w + dx >= 0 && w + dx < WN) {
                int q = p + dy * WN + dx;
                sim = Dj[p] / fmaxf(nc * sqrtf(D[q]), EPSV);
            }
            count += (sim < t2) ? 1 : 0;
        }
        // negative direction: neighbor q = p - d; dot stored at q
        {
            float sim = 0.f;
            if (h - dy >= 0 && w - dx >= 0 && w - dx < WN) {
                int q = p - (dy * WN + dx);
                sim = Dj[q] / fmaxf(nc * sqrtf(D[q]), EPSV);
            }
            count += (sim < t2) ? 1 : 0;
        }
    }
    float s = 1.f + sqrtf((float)count);

    constexpr int CG = CN / CSPLIT;
    const float* xp = x   + ((size_t)b * CN + (size_t)cg * CG) * HW + hw;
    float*       op = out + ((size_t)b * CN + (size_t)cg * CG) * HW + hw;
#pragma unroll 8
    for (int c = 0; c < CG; ++c)
        op[(size_t)c * HW] = xp[(size_t)c * HW] * s;
}

extern "C" void kernel_launch(void* const* d_in, const int* in_sizes, int n_in,
                              void* d_out, int out_size, void* d_ws, size_t ws_size,
                              hipStream_t stream) {
    const float* x    = (const float*)d_in[0];
    // d_in[1] = edge_threshold1: unused — cosine sim is invariant under the
    // per-pixel positive rescale x_mask = x*(1+m1), so the 9x9 pass is dead.
    const float* thr2 = (const float*)d_in[2];
    float* out = (float*)d_out;

    float* D = (float*)d_ws;                           // NMAP*NPIX floats (~958 KB)

    k_maps<<<dim3(NP4 / 8), dim3(8, 32), 0, stream>>>(x, D);
    k_maskapply<4><<<dim3(NPIX / 64, 4), 64, 0, stream>>>(x, D, thr2, out);
}

// Round 5
// 87.418 us; speedup vs baseline: 3.2234x; 1.0058x over previous
//
#include <hip/hip_runtime.h>

// x is (B=2, C=128, H=96, W=96) fp32.
#define BN   2
#define CN   128
#define HN   96
#define WN   96
#define HW   (HN * WN)          // 9216
#define NPIX (BN * HW)          // 18432
#define NP4  (NPIX / 4)         // 4608
#define NMAP 13                 // map 0 = norm^2, maps 1..12 = positive-offset dots
#define EPSV 1e-8f

// Positive half-plane offsets (dy,dx), maps 1..12. dot(p, p+d) == dot(p+d, p).
constexpr int ODY[12] = {0, 0, 1, 1, 1, 1, 1, 2, 2, 2, 2, 2};
constexpr int ODX[12] = {1, 2, -2, -1, 0, 1, 2, -2, -1, 0, 1, 2};

// Kernel 1: full dot/norm maps D[13][NPIX] in one pass.
// Block = (8 px4-lanes x 32 channel-slices), 4 channels per slice.
// Grid = 576 blocks = 2304 waves = 9 waves/CU.
// Per channel the needed window is cols w-2..w+5 per row: float2+float4+float2
// (row 0 needs only cols w..w+5: the dy=0 maps have dx>0). 8 loads, 88 B per
// channel vs 9/144 before. Cross-slice sum via float4 LDS staged reduction
// (17-float4 stride => b128 conflict-free). OOB rows/cols contribute 0.
__global__ void __launch_bounds__(256) k_maps(const float* __restrict__ x,
                                              float* __restrict__ D) {
    const int tx = threadIdx.x;                        // 0..7  (px4 lane)
    const int ty = threadIdx.y;                        // 0..31 (channel slice)
    int p4 = blockIdx.x * 8 + tx;                      // 0..NP4-1
    int pix = p4 * 4;
    int b = pix / HW;
    int hw = pix - b * HW;
    int h = hw / WN;
    int w = hw - h * WN;                               // multiple of 4
    const float* xb = x + ((size_t)b * CN + (size_t)ty * 4) * HW + h * WN + w;

    float acc[NMAP][4];
#pragma unroll
    for (int m = 0; m < NMAP; ++m)
#pragma unroll
        for (int i = 0; i < 4; ++i) acc[m][i] = 0.f;

#pragma unroll
    for (int cc = 0; cc < 4; ++cc) {
        const float* cp = xb + (size_t)cc * HW;
        float r[3][8];                                 // cols w-2 .. w+5
        {   // row 0 (always in-bounds): only cols w..w+5 needed
            float4 a1 = *(const float4*)cp;            // cols w..w+3
            float2 hi = make_float2(0.f, 0.f);
            if (w + 4 < WN) hi = *(const float2*)(cp + 4);   // cols w+4,w+5
            r[0][0] = 0.f;  r[0][1] = 0.f;
            r[0][2] = a1.x; r[0][3] = a1.y; r[0][4] = a1.z; r[0][5] = a1.w;
            r[0][6] = hi.x; r[0][7] = hi.y;
        }
#pragma unroll
        for (int ry = 1; ry < 3; ++ry) {
            float2 lo = make_float2(0.f, 0.f);
            float4 a1 = make_float4(0.f, 0.f, 0.f, 0.f);
            float2 hi = make_float2(0.f, 0.f);
            if (h + ry < HN) {
                const float* rp = cp + ry * WN;
                if (w > 0)      lo = *(const float2*)(rp - 2);   // cols w-2,w-1
                a1 = *(const float4*)rp;                          // cols w..w+3
                if (w + 4 < WN) hi = *(const float2*)(rp + 4);   // cols w+4,w+5
            }
            r[ry][0] = lo.x; r[ry][1] = lo.y;
            r[ry][2] = a1.x; r[ry][3] = a1.y; r[ry][4] = a1.z; r[ry][5] = a1.w;
            r[ry][6] = hi.x; r[ry][7] = hi.y;
        }
#pragma unroll
        for (int i = 0; i < 4; ++i) {
            float c = r[0][2 + i];
            acc[0][i] += c * c;
#pragma unroll
            for (int j = 0; j < 12; ++j)
                acc[j + 1][i] += c * r[ODY[j]][2 + i + ODX[j]];
        }
    }

    // Staged float4 LDS reduction over the 32 slices: 16->8->4->2->1.
    // Inner stride 17 float4s = 68 dwords; 68 mod 32 = 4 -> consecutive tx
    // start 4 banks apart -> conflict-free b128.
    __shared__ float4 red[16][8][17];
#pragma unroll
    for (int s = 16; s >= 1; s >>= 1) {
        if (ty >= s && ty < 2 * s) {
#pragma unroll
            for (int m = 0; m < NMAP; ++m)
                red[ty - s][tx][m] =
                    make_float4(acc[m][0], acc[m][1], acc[m][2], acc[m][3]);
        }
        __syncthreads();
        if (ty < s) {
#pragma unroll
            for (int m = 0; m < NMAP; ++m) {
                float4 v = red[ty][tx][m];
                acc[m][0] += v.x; acc[m][1] += v.y;
                acc[m][2] += v.z; acc[m][3] += v.w;
            }
        }
        __syncthreads();
    }

    if (ty == 0) {
#pragma unroll
        for (int m = 0; m < NMAP; ++m)
            *(float4*)(D + (size_t)m * NPIX + pix) =
                make_float4(acc[m][0], acc[m][1], acc[m][2], acc[m][3]);
    }
}

// Kernel 2: fused count + apply. Thread = (pixel, channel-eighth).
// mask = sqrt(#{sim < t2}) from the 13 maps, then stream 16 channels:
// out = x * (1 + mask). OOB neighbor -> sim = 0 -> always counted.
template<int CSPLIT>
__global__ void __launch_bounds__(64) k_maskapply(const float* __restrict__ x,
                                                  const float* __restrict__ D,
                                                  const float* __restrict__ thr2p,
                                                  float* __restrict__ out) {
    int p = blockIdx.x * blockDim.x + threadIdx.x;     // pixel
    if (p >= NPIX) return;
    int cg = blockIdx.y;
    const float t2 = *thr2p;
    int b = p / HW;
    int hw = p - b * HW;
    int h = hw / WN, w = hw - h * WN;

    float nc = sqrtf(D[p]);                            // map 0 = norm^2
    int count = 0;
#pragma unroll
    for (int j = 0; j < 12; ++j) {
        const int dy = ODY[j], dx = ODX[j];
        const float* Dj = D + (size_t)(j + 1) * NPIX;
        // positive direction: neighbor (h+dy, w+dx); dot stored at p
        {
            float sim = 0.f;
            if (h + dy < HN && w + dx >= 0 && w + dx < WN) {
                int q = p + dy * WN + dx;
                sim = Dj[p] / fmaxf(nc * sqrtf(D[q]), EPSV);
            }
            count += (sim < t2) ? 1 : 0;
        }
        // negative direction: neighbor q = p - d; dot stored at q
        {
            float sim = 0.f;
            if (h - dy >= 0 && w - dx >= 0 && w - dx < WN) {
                int q = p - (dy * WN + dx);
                sim = Dj[q] / fmaxf(nc * sqrtf(D[q]), EPSV);
            }
            count += (sim < t2) ? 1 : 0;
        }
    }
    float s = 1.f + sqrtf((float)count);

    constexpr int CG = CN / CSPLIT;
    const float* xp = x   + ((size_t)b * CN + (size_t)cg * CG) * HW + hw;
    float*       op = out + ((size_t)b * CN + (size_t)cg * CG) * HW + hw;
#pragma unroll
    for (int c = 0; c < CG; ++c)
        op[(size_t)c * HW] = xp[(size_t)c * HW] * s;
}

extern "C" void kernel_launch(void* const* d_in, const int* in_sizes, int n_in,
                              void* d_out, int out_size, void* d_ws, size_t ws_size,
                              hipStream_t stream) {
    const float* x    = (const float*)d_in[0];
    // d_in[1] = edge_threshold1: unused — cosine sim is invariant under the
    // per-pixel positive rescale x_mask = x*(1+m1), so the 9x9 pass is dead.
    const float* thr2 = (const float*)d_in[2];
    float* out = (float*)d_out;

    float* D = (float*)d_ws;                           // NMAP*NPIX floats (~958 KB)

    k_maps<<<dim3(NP4 / 8), dim3(8, 32), 0, stream>>>(x, D);
    k_maskapply<8><<<dim3(NPIX / 64, 8), 64, 0, stream>>>(x, D, thr2, out);
}